// Round 1
// baseline (5646.495 us; speedup 1.0000x reference)
//
#include <hip/hip_runtime.h>
#include <hip/hip_bf16.h>

#define Hdim 1024
#define Bsz  64
#define TST  127
#define NWG  128
#define NTHR 256
#define NCLS 50000

typedef __attribute__((ext_vector_type(8))) short s8v;   // 8 x bf16 fragment
typedef __attribute__((ext_vector_type(4))) float f4v;   // MFMA accumulator

// ---- workspace layout (bytes) ----
#define OFF_X0   0ull
#define SZ_X0    ((unsigned long long)TST * Bsz * Hdim * 4ull)   // 33,292,288
#define OFF_HB   (OFF_X0 + SZ_X0)                                // bf16 [64*1024]
#define OFF_N1   (OFF_HB  + 131072ull)
#define OFF_N3   (OFF_N1  + 131072ull)
#define OFF_N5   (OFF_N3  + 131072ull)
#define OFF_N2F  (OFF_N5  + 131072ull)                           // f32 [64*1024]
#define OFF_N4F  (OFF_N2F + 262144ull)
#define OFF_W0B  (OFF_N4F + 262144ull)                           // bf16 W0 [1024*1024]
#define OFF_BAR  (OFF_W0B + 2097152ull)                          // barrier cnt/flag
#define WS_NEED  (OFF_BAR + 256ull)

__device__ __forceinline__ unsigned short f2b(float f) {
  union { float f; unsigned u; } v; v.f = f;
  return (unsigned short)((v.u + 0x7FFFu + ((v.u >> 16) & 1u)) >> 16);  // RNE
}
__device__ __forceinline__ float fast_tanh(float x) {
  return 1.f - 2.f / (__expf(2.f * x) + 1.f);
}
__device__ __forceinline__ float fast_sigm(float x) {
  return 1.f / (1.f + __expf(-x));
}
__device__ __forceinline__ s8v pack8(const float* __restrict__ p) {
  s8v r;
#pragma unroll
  for (int i = 0; i < 8; ++i) r[i] = (short)f2b(p[i]);
  return r;
}

// ---------------- W0 fp32 -> bf16 ----------------
__global__ __launch_bounds__(256) void k_cvt(const float* __restrict__ src,
                                             unsigned short* __restrict__ dst) {
  const int i = (blockIdx.x * 256 + threadIdx.x) * 4;
  float4 v = *(const float4*)(src + i);
  ushort4 o; o.x = f2b(v.x); o.y = f2b(v.y); o.z = f2b(v.z); o.w = f2b(v.w);
  *(ushort4*)(dst + i) = o;
}

// ---------------- X0[t] = emb[idx[:,t+1]] @ W0^T + b0 + bs0 (parallel over t) ----------------
__global__ __launch_bounds__(256) void k_x0(const float* __restrict__ emb,
                                            const int* __restrict__ ids,
                                            const unsigned short* __restrict__ w0b,
                                            const float* __restrict__ b0,
                                            const float* __restrict__ bs,
                                            float* __restrict__ x0) {
  const int t  = blockIdx.x;            // 0..126
  const int cb = blockIdx.y * 256;      // column base
  const int lane = threadIdx.x & 63, wvv = threadIdx.x >> 6;
  const int lc = lane & 15, lg = lane >> 4;
  const int cw = cb + wvv * 64;         // this wave: 4 col-tiles of 16
  const float* erow[4];
#pragma unroll
  for (int rt = 0; rt < 4; ++rt)
    erow[rt] = emb + (size_t)ids[(rt * 16 + lc) * 128 + t + 1] * Hdim + lg * 8;
  f4v acc[4][4];
#pragma unroll
  for (int rt = 0; rt < 4; ++rt)
#pragma unroll
    for (int ct = 0; ct < 4; ++ct) acc[rt][ct] = (f4v){0.f, 0.f, 0.f, 0.f};

  for (int ks = 0; ks < 32; ++ks) {
    s8v a[4];
#pragma unroll
    for (int rt = 0; rt < 4; ++rt) a[rt] = pack8(erow[rt] + ks * 32);
#pragma unroll
    for (int ct = 0; ct < 4; ++ct) {
      s8v b = *(const s8v*)(w0b + (size_t)(cw + ct * 16 + lc) * Hdim + ks * 32 + lg * 8);
#pragma unroll
      for (int rt = 0; rt < 4; ++rt)
        acc[rt][ct] = __builtin_amdgcn_mfma_f32_16x16x32_bf16(a[rt], b, acc[rt][ct], 0, 0, 0);
    }
  }
  float* xt = x0 + (size_t)t * (Bsz * Hdim);
#pragma unroll
  for (int ct = 0; ct < 4; ++ct) {
    const int col = cw + ct * 16 + lc;
    const float bias = b0[col] + bs[col];   // bs row 0
#pragma unroll
    for (int rt = 0; rt < 4; ++rt)
#pragma unroll
      for (int j = 0; j < 4; ++j)
        xt[(rt * 16 + lg * 4 + j) * Hdim + col] = acc[rt][ct][j] + bias;
  }
}

// ---------------- grid barrier (agent-scope, phase-counting) ----------------
__device__ __forceinline__ void gbar(unsigned* cnt, unsigned* flg, unsigned target) {
  __syncthreads();
  if (threadIdx.x == 0) {
    unsigned prev = __hip_atomic_fetch_add(cnt, 1u, __ATOMIC_ACQ_REL, __HIP_MEMORY_SCOPE_AGENT);
    if (prev == NWG - 1u) {
      __hip_atomic_store(cnt, 0u, __ATOMIC_RELAXED, __HIP_MEMORY_SCOPE_AGENT);
      __hip_atomic_store(flg, target, __ATOMIC_RELEASE, __HIP_MEMORY_SCOPE_AGENT);
    } else {
      while (__hip_atomic_load(flg, __ATOMIC_RELAXED, __HIP_MEMORY_SCOPE_AGENT) < target)
        __builtin_amdgcn_s_sleep(2);
      __threadfence();   // acquire: invalidate L1/L2 so fresh activations are read
    }
  }
  __syncthreads();
}

// out[64,16] slab = in[64,1024] @ Wslice^T, weights in LDS tiled [K/8][16][8]
__device__ __forceinline__ f4v slice_mm(const unsigned short* __restrict__ in_b,
                                        const unsigned short* ldw,
                                        int lc, int lg, int wvv) {
  f4v acc = (f4v){0.f, 0.f, 0.f, 0.f};
  const unsigned short* ar = in_b + (wvv * 16 + lc) * Hdim + lg * 8;
  const unsigned short* br = ldw + lg * 128 + lc * 8;
#pragma unroll 8
  for (int ks = 0; ks < 32; ++ks) {
    s8v a = *(const s8v*)(ar + ks * 32);
    s8v b = *(const s8v*)(br + ks * 512);
    acc = __builtin_amdgcn_mfma_f32_16x16x32_bf16(a, b, acc, 0, 0, 0);
  }
  return acc;
}

// ---------------- persistent scan: 127 steps x 4 levels ----------------
__global__ __launch_bounds__(256, 1) void k_scan(const float* __restrict__ Ws,
                                                 const float* __restrict__ bs,
                                                 const float* __restrict__ h_in,
                                                 const float* __restrict__ Wsum,
                                                 const float* __restrict__ bsum,
                                                 const float* __restrict__ act,
                                                 char* __restrict__ ws) {
  __shared__ unsigned short lds[3 * 16384];   // 96 KiB: three [1024 x 16] bf16 slices
  const int w = blockIdx.x;
  const int half = w >> 6;          // 0: {M0,M1,M3}, 1: {M2,M4,M5}
  const int c0 = (w & 63) * 16;
  const int tid = threadIdx.x;
  const int lane = tid & 63, wvv = tid >> 6;
  const int lc = lane & 15, lg = lane >> 4;

  unsigned short* hb  = (unsigned short*)(ws + OFF_HB);
  unsigned short* n1b = (unsigned short*)(ws + OFF_N1);
  unsigned short* n3b = (unsigned short*)(ws + OFF_N3);
  unsigned short* n5b = (unsigned short*)(ws + OFF_N5);
  float* n2f = (float*)(ws + OFF_N2F);
  float* n4f = (float*)(ws + OFF_N4F);
  const float* x0 = (const float*)(ws + OFF_X0);
  unsigned* bar_cnt = (unsigned*)(ws + OFF_BAR);
  unsigned* bar_flg = (unsigned*)(ws + OFF_BAR + 128);

  // load 3 weight slices (fp32 global -> bf16 LDS, tiled [k/8][16][8])
  const int m0 = (half == 0) ? 0 : 2;
  const int m1 = (half == 0) ? 1 : 4;
  const int m2 = (half == 0) ? 3 : 5;
  const int mats[3] = {m0, m1, m2};
#pragma unroll
  for (int s = 0; s < 3; ++s) {
    const float* msrc = Ws + (size_t)mats[s] * (Hdim * Hdim);
    unsigned short* dst = lds + s * 16384;
    for (int i = tid; i < 4096; i += NTHR) {
      const int c = i >> 8, k4 = i & 255;
      float4 v = *(const float4*)(msrc + (size_t)(c0 + c) * Hdim + k4 * 4);
      ushort4 o; o.x = f2b(v.x); o.y = f2b(v.y); o.z = f2b(v.z); o.w = f2b(v.w);
      *(ushort4*)(dst + ((k4 >> 1) * 16 + c) * 8 + (k4 & 1) * 4) = o;
    }
  }
  // per-lane biases for this WG's columns
  float bias_a, bias_b, bias_c = 0.f;
  if (half == 0) { bias_a = bs[1 * Hdim + c0 + lc]; bias_b = bs[3 * Hdim + c0 + lc]; }
  else { bias_a = bs[2 * Hdim + c0 + lc]; bias_b = bs[4 * Hdim + c0 + lc]; bias_c = bs[5 * Hdim + c0 + lc]; }

  // softmax combine weights over nodes {2,4,6} -> weight idx {1,3,5}
  float cw[3];
#pragma unroll
  for (int j = 0; j < 3; ++j) {
    const int i = 2 * j + 1;
    float s = bsum[i];
    for (int a2 = 0; a2 < 12; ++a2) s += Wsum[i * 12 + a2] * act[a2];
    cw[j] = s;
  }
  {
    float m = fmaxf(cw[0], fmaxf(cw[1], cw[2]));
    float e0 = __expf(cw[0] - m), e1 = __expf(cw[1] - m), e2 = __expf(cw[2] - m);
    float inv = 1.f / (e0 + e1 + e2);
    cw[0] = e0 * inv; cw[1] = e1 * inv; cw[2] = e2 * inv;
  }

  // initial h fp32 -> bf16
  {
    const int base = w * 512 + tid * 2;
    hb[base]     = f2b(h_in[base]);
    hb[base + 1] = f2b(h_in[base + 1]);
  }

  unsigned phase = 1;
  gbar(bar_cnt, bar_flg, phase++);

  for (int t = 0; t < TST; ++t) {
    // L1: n1 = tanh(h @ M0^T + X0[t])   (X0 already contains b0+bs0)
    if (half == 0) {
      f4v acc = slice_mm(hb, lds, lc, lg, wvv);
      const float* xt = x0 + (size_t)t * (Bsz * Hdim);
#pragma unroll
      for (int j = 0; j < 4; ++j) {
        const int row = wvv * 16 + lg * 4 + j;
        n1b[row * Hdim + c0 + lc] = f2b(fast_tanh(acc[j] + xt[row * Hdim + c0 + lc]));
      }
    }
    gbar(bar_cnt, bar_flg, phase++);

    // L2: n2 = relu(n1@M1^T+b1) [half0] ; n3 = sigmoid(n1@M2^T+b2) [half1]
    if (half == 0) {
      f4v acc = slice_mm(n1b, lds + 16384, lc, lg, wvv);
#pragma unroll
      for (int j = 0; j < 4; ++j) {
        const int row = wvv * 16 + lg * 4 + j;
        n2f[row * Hdim + c0 + lc] = fmaxf(acc[j] + bias_a, 0.f);
      }
    } else {
      f4v acc = slice_mm(n1b, lds, lc, lg, wvv);
#pragma unroll
      for (int j = 0; j < 4; ++j) {
        const int row = wvv * 16 + lg * 4 + j;
        n3b[row * Hdim + c0 + lc] = f2b(fast_sigm(acc[j] + bias_a));
      }
    }
    gbar(bar_cnt, bar_flg, phase++);

    // L3: n4 = tanh(n3@M3^T+b3) [half0] ; n5 = relu(n3@M4^T+b4) [half1]
    if (half == 0) {
      f4v acc = slice_mm(n3b, lds + 32768, lc, lg, wvv);
#pragma unroll
      for (int j = 0; j < 4; ++j) {
        const int row = wvv * 16 + lg * 4 + j;
        n4f[row * Hdim + c0 + lc] = fast_tanh(acc[j] + bias_b);
      }
    } else {
      f4v acc = slice_mm(n3b, lds + 16384, lc, lg, wvv);
#pragma unroll
      for (int j = 0; j < 4; ++j) {
        const int row = wvv * 16 + lg * 4 + j;
        n5b[row * Hdim + c0 + lc] = f2b(fmaxf(acc[j] + bias_b, 0.f));
      }
    }
    gbar(bar_cnt, bar_flg, phase++);

    // L4: n6 = tanh(n5@M5^T+b5); h = cw0*n2 + cw1*n4 + cw2*n6  [half1]
    if (half == 1) {
      f4v acc = slice_mm(n5b, lds + 32768, lc, lg, wvv);
#pragma unroll
      for (int j = 0; j < 4; ++j) {
        const int row = wvv * 16 + lg * 4 + j;
        const int col = c0 + lc;
        const float v6 = fast_tanh(acc[j] + bias_c);
        const float hv = cw[0] * n2f[row * Hdim + col] + cw[1] * n4f[row * Hdim + col] + cw[2] * v6;
        hb[row * Hdim + col] = f2b(hv);
      }
    }
    gbar(bar_cnt, bar_flg, phase++);
  }
}

// ---------------- epilogue: out = h @ W_out^T + b_out ----------------
__global__ __launch_bounds__(256) void k_out(const unsigned short* __restrict__ hb,
                                             const float* __restrict__ wout,
                                             const float* __restrict__ bout,
                                             float* __restrict__ out) {
  const int cb = blockIdx.x * 128;
  const int lane = threadIdx.x & 63, wvv = threadIdx.x >> 6;
  const int lc = lane & 15, lg = lane >> 4;
  const int cw = cb + wvv * 32;
  f4v acc[4][2];
#pragma unroll
  for (int rt = 0; rt < 4; ++rt)
#pragma unroll
    for (int ct = 0; ct < 2; ++ct) acc[rt][ct] = (f4v){0.f, 0.f, 0.f, 0.f};

  for (int ks = 0; ks < 32; ++ks) {
    s8v a[4];
#pragma unroll
    for (int rt = 0; rt < 4; ++rt)
      a[rt] = *(const s8v*)(hb + (rt * 16 + lc) * Hdim + ks * 32 + lg * 8);
#pragma unroll
    for (int ct = 0; ct < 2; ++ct) {
      const int col = cw + ct * 16 + lc;
      const int cs = col < NCLS ? col : NCLS - 1;
      s8v b = pack8(wout + (size_t)cs * Hdim + ks * 32 + lg * 8);
#pragma unroll
      for (int rt = 0; rt < 4; ++rt)
        acc[rt][ct] = __builtin_amdgcn_mfma_f32_16x16x32_bf16(a[rt], b, acc[rt][ct], 0, 0, 0);
    }
  }
#pragma unroll
  for (int ct = 0; ct < 2; ++ct) {
    const int col = cw + ct * 16 + lc;
    if (col < NCLS) {
      const float bias = bout[col];
#pragma unroll
      for (int rt = 0; rt < 4; ++rt)
#pragma unroll
        for (int j = 0; j < 4; ++j)
          out[(size_t)(rt * 16 + lg * 4 + j) * NCLS + col] = acc[rt][ct][j] + bias;
    }
  }
}

extern "C" void kernel_launch(void* const* d_in, const int* in_sizes, int n_in,
                              void* d_out, int out_size, void* d_ws, size_t ws_size,
                              hipStream_t stream) {
  (void)in_sizes; (void)n_in; (void)out_size;
  if (ws_size < WS_NEED) return;   // fail loudly via absmax rather than corrupt memory

  const float* emb  = (const float*)d_in[0];
  const float* h0   = (const float*)d_in[1];
  const int*   ids  = (const int*)d_in[2];
  const float* W0   = (const float*)d_in[3];
  const float* b0   = (const float*)d_in[4];
  const float* Ws   = (const float*)d_in[5];
  const float* bsp  = (const float*)d_in[6];
  const float* Wout = (const float*)d_in[7];
  const float* bout = (const float*)d_in[8];
  const float* Wsum = (const float*)d_in[9];
  const float* bsum = (const float*)d_in[10];
  const float* act  = (const float*)d_in[11];
  char* ws  = (char*)d_ws;
  float* out = (float*)d_out;

  hipMemsetAsync(ws + OFF_BAR, 0, 256, stream);                       // barrier state
  k_cvt<<<1024, 256, 0, stream>>>(W0, (unsigned short*)(ws + OFF_W0B));
  k_x0<<<dim3(TST, 4), 256, 0, stream>>>(emb, ids, (const unsigned short*)(ws + OFF_W0B),
                                         b0, bsp, (float*)(ws + OFF_X0));

  void* args[] = { (void*)&Ws, (void*)&bsp, (void*)&h0, (void*)&Wsum,
                   (void*)&bsum, (void*)&act, (void*)&ws };
  hipLaunchCooperativeKernel((void*)k_scan, dim3(NWG), dim3(NTHR), args, 0, stream);

  k_out<<<391, 256, 0, stream>>>((const unsigned short*)(ws + OFF_HB), Wout, bout, out);
}